// Round 15
// baseline (260.324 us; speedup 1.0000x reference)
//
#include <hip/hip_runtime.h>
#include <hip/hip_bf16.h>
#include <stdint.h>

#define B_ 2
#define S_ 2048
#define E_ 1024
#define H_ 16
#define D_ 64
#define LOG2E 1.4426950408889634f

typedef unsigned short ubf;
typedef __attribute__((ext_vector_type(8))) short bh8;    // 8 bf16 (4 VGPRs) MFMA A/B frag
typedef __attribute__((ext_vector_type(4))) float fx4;    // 16x16 C/D frag
typedef __attribute__((ext_vector_type(16))) float fx16;  // 32x32 C/D frag

__device__ __forceinline__ ubf f2bf(float f) {
  unsigned u = __float_as_uint(f);
  unsigned r = (u + 0x7fffu + ((u >> 16) & 1u)) >> 16;  // RNE
  return (ubf)r;
}

__device__ __forceinline__ unsigned cvtpk(float lo, float hi2) {
  unsigned r;
  asm("v_cvt_pk_bf16_f32 %0, %1, %2" : "=v"(r) : "v"(lo), "v"(hi2));
  return r;
}

// validated r4: after pl32swap(a,b): a = [a.low32 | b.low32], b = [a.high32 | b.high32]
__device__ __forceinline__ void pl32swap(unsigned& a, unsigned& b) {
  asm("v_permlane32_swap_b32 %0, %1" : "+v"(a), "+v"(b));
}

__device__ __forceinline__ void gl_lds16(const void* g, void* l) {
  __builtin_amdgcn_global_load_lds(
      (const __attribute__((address_space(1))) void*)g,
      (__attribute__((address_space(3))) void*)l, 16, 0, 0);
}

// ---------------- prepass: z<3: fp32->bf16 convert of q/k/v; z=3: mask scan
__global__ void prep(const float* __restrict__ q, const float* __restrict__ k,
                     const float* __restrict__ v, const float* __restrict__ mask,
                     ubf* __restrict__ dst0, int* __restrict__ flagarr) {
  const int z = blockIdx.z;
  const int tid = threadIdx.x;
  const int stride = gridDim.x * blockDim.x;
  if (z == 3) {
    int any = 0;
    const int n4m = (B_ * S_ * S_) / 4;
    for (int j = blockIdx.x * blockDim.x + tid; j < n4m; j += stride) {
      float4 x = ((const float4*)mask)[j];
      any |= (x.x != 0.f) | (x.y != 0.f) | (x.z != 0.f) | (x.w != 0.f);
    }
    int wany = __any(any != 0) ? 1 : 0;
    if ((tid & 63) == 0) flagarr[blockIdx.x * 4 + (tid >> 6)] = wany;
    return;
  }
  const float* src = (z == 0) ? q : (z == 1) ? k : v;
  ubf* dst = dst0 + (size_t)z * (B_ * S_ * E_);
  const int n4 = (B_ * S_ * E_) / 4;
  for (int j = blockIdx.x * blockDim.x + tid; j < n4; j += stride) {
    float4 x = ((const float4*)src)[j];
    ushort4 o;
    o.x = f2bf(x.x); o.y = f2bf(x.y); o.z = f2bf(x.z); o.w = f2bf(x.w);
    ((ushort4*)dst)[j] = o;
  }
}

// ---------------- prepass: weight transpose+convert  Wt[n][k] = W[k][n] (bf16)
__global__ void wtrans4(const float* __restrict__ Wq, const float* __restrict__ Wk,
                        const float* __restrict__ Wv, const float* __restrict__ Wo,
                        ubf* __restrict__ Wt0) {
  __shared__ float t[32][33];
  int z = blockIdx.z;
  const float* W = (z == 0) ? Wq : (z == 1) ? Wk : (z == 2) ? Wv : Wo;
  ubf* Wt = Wt0 + (size_t)z * (E_ * E_);
  int kb = blockIdx.x, nb = blockIdx.y;
  int c = threadIdx.x & 31, r0 = threadIdx.x >> 5;
#pragma unroll
  for (int rr = 0; rr < 32; rr += 8)
    t[r0 + rr][c] = W[(size_t)(kb * 32 + r0 + rr) * E_ + nb * 32 + c];
  __syncthreads();
#pragma unroll
  for (int rr = 0; rr < 32; rr += 8)
    Wt[(size_t)(nb * 32 + r0 + rr) * E_ + kb * 32 + c] = f2bf(t[c][r0 + rr]);
}

// ================= fused QKV projection GEMM, r15: ZERO-LDS direct-L2 =====
// Every lane loads its own A/B MFMA fragments straight from global (L2-resident
// via T1 XCD swizzle). No LDS, no barriers, no vmcnt asm — waves free-run and
// the compiler software-pipelines the 6 dwordx4 loads against 8 MFMAs per step.
// Per-lane mapping identical to the de-swizzled LDS read of r10:
//   a[m] = A[(bm*128+wm*64+m*16+c15)*K + t*32 + g*8]  (4-lane groups = 64B segs)
__global__ void __launch_bounds__(256, 5)
gemm_qkv(const ubf* __restrict__ X, const ubf* __restrict__ Wt,
         const float* __restrict__ bq, const float* __restrict__ bk,
         const float* __restrict__ bv, ubf* __restrict__ Out) {
  constexpr int K = 1024;
  const int z = blockIdx.z;
  const ubf* A  = (z == 2) ? (Wt + 2u * 1048576u) : (X + (size_t)z * 4194304u);
  const ubf* Bt = (z == 2) ? (X + 2u * 4194304u) : (Wt + (size_t)z * 1048576u);
  const float* bias = (z == 0) ? bq : (z == 1) ? bk : bv;
  ubf* Cout = Out + (size_t)z * 4194304u;

  const int bx0 = blockIdx.x;
  const int swz = (bx0 & 7) * 64 + (bx0 >> 3);  // T1 XCD-contiguous chunks (r10)
  int bm, bn;
  if (z == 2) {
    bm = (swz >> 3) & 7;
    bn = ((swz >> 6) << 3) | (swz & 7);
  } else {
    bm = swz >> 4;
    bn = swz & 15;
  }

  const int tid = threadIdx.x;
  const int lane = tid & 63, w = tid >> 6;
  const int wm = w >> 1, wn = w & 1;
  const int g = lane >> 4, c15 = lane & 15;

  const fx4 FZ = {0.f, 0.f, 0.f, 0.f};
  fx4 acc[4][2];
#pragma unroll
  for (int m = 0; m < 4; m++)
#pragma unroll
    for (int n = 0; n < 2; n++) acc[m][n] = FZ;

  // per-lane fragment base pointers
  const ubf* Ap = A + (size_t)(bm * 128 + wm * 64 + c15) * K + g * 8;
  const ubf* Bp = Bt + (size_t)(bn * 64 + wn * 32 + c15) * K + g * 8;

#pragma unroll 4
  for (int t = 0; t < K / 32; t++) {
    const int ko = t * 32;
    bh8 a[4], b[2];
#pragma unroll
    for (int m = 0; m < 4; m++)
      a[m] = *(const bh8*)(Ap + (size_t)(m * 16) * K + ko);
#pragma unroll
    for (int n = 0; n < 2; n++)
      b[n] = *(const bh8*)(Bp + (size_t)(n * 16) * K + ko);
    __builtin_amdgcn_s_setprio(1);
#pragma unroll
    for (int m = 0; m < 4; m++)
#pragma unroll
      for (int n = 0; n < 2; n++)
        acc[m][n] = __builtin_amdgcn_mfma_f32_16x16x32_bf16(a[m], b[n], acc[m][n], 0, 0, 0);
    __builtin_amdgcn_s_setprio(0);
  }

#pragma unroll
  for (int m = 0; m < 4; m++) {
    int rbase = bm * 128 + wm * 64 + m * 16 + g * 4;
#pragma unroll
    for (int n = 0; n < 2; n++) {
      int col = bn * 64 + wn * 32 + n * 16 + c15;
#pragma unroll
      for (int r = 0; r < 4; r++) {
        int mrow = rbase + r;
        float val = acc[m][n][r];
        if (z <= 1) {
          val = val + bias[col];
          if (z == 0) val *= 0.125f * LOG2E;  // fold 1/sqrt(D) and log2 domain
          int bb = mrow >> 11, ss = mrow & 2047, hh = col >> 6, dd = col & 63;
          Cout[((size_t)(bb * H_ + hh) * S_ + ss) * D_ + dd] = f2bf(val);
        } else {
          val = val + bias[mrow];
          int bb = col >> 11, ss = col & 2047, hh = mrow >> 6, dd = mrow & 63;
          Cout[((size_t)(bb * H_ + hh) * D_ + dd) * S_ + ss] = f2bf(val);
        }
      }
    }
  }
}

// ================= output GEMM, r15: ZERO-LDS direct-L2 (64x64 tile) =====
__global__ void __launch_bounds__(256, 6)
gemm_out(const ubf* __restrict__ A, const ubf* __restrict__ Bt,
         const float* __restrict__ bias, float* __restrict__ Cout, int N) {
  constexpr int K = 1024;
  const int tid = threadIdx.x;
  const int lane = tid & 63, w = tid >> 6;
  const int wm = w >> 1, wn = w & 1;
  const int bid = blockIdx.x;
  const int swz = (bid & 7) * 128 + (bid >> 3);  // T1
  const int bm = swz >> 4, bn = swz & 15;
  const int g = lane >> 4, c15 = lane & 15;

  const fx4 FZ = {0.f, 0.f, 0.f, 0.f};
  fx4 acc[2][2];
#pragma unroll
  for (int m = 0; m < 2; m++)
#pragma unroll
    for (int n = 0; n < 2; n++) acc[m][n] = FZ;

  const ubf* Ap = A + (size_t)(bm * 64 + wm * 32 + c15) * K + g * 8;
  const ubf* Bp = Bt + (size_t)(bn * 64 + wn * 32 + c15) * K + g * 8;

#pragma unroll 4
  for (int t = 0; t < K / 32; t++) {
    const int ko = t * 32;
    bh8 a[2], b[2];
#pragma unroll
    for (int m = 0; m < 2; m++)
      a[m] = *(const bh8*)(Ap + (size_t)(m * 16) * K + ko);
#pragma unroll
    for (int n = 0; n < 2; n++)
      b[n] = *(const bh8*)(Bp + (size_t)(n * 16) * K + ko);
    __builtin_amdgcn_s_setprio(1);
#pragma unroll
    for (int m = 0; m < 2; m++)
#pragma unroll
      for (int n = 0; n < 2; n++)
        acc[m][n] = __builtin_amdgcn_mfma_f32_16x16x32_bf16(a[m], b[n], acc[m][n], 0, 0, 0);
    __builtin_amdgcn_s_setprio(0);
  }

#pragma unroll
  for (int m = 0; m < 2; m++) {
    int rbase = bm * 64 + wm * 32 + m * 16 + g * 4;
#pragma unroll
    for (int n = 0; n < 2; n++) {
      int col = bn * 64 + wn * 32 + n * 16 + c15;
#pragma unroll
      for (int r = 0; r < 4; r++)
        Cout[(size_t)(rbase + r) * N + col] = acc[m][n][r] + bias[col];
    }
  }
}

// ================= flash attention =================
// Q[B,H,S,D] (pre-scaled by 0.125*LOG2E), K[B,H,S,D], V^T[B,H,D,S]
// Swapped QK^T: lane owns q = lane&31; key row = ROWQ(r).
// C/D map (32x32): col=lane&31, row=(r&3)+8*(r>>2)+4*(lane>>5)   [m74/m101]
#define ROWQ(r) (((r) & 3) + 8 * ((r) >> 2) + 4 * hi)

// ---- fast path: 512 threads = 2 KV-groups x 4 waves; in-block LDS merge.
// Writes AO bf16 directly — no fp32 partials, no combine kernel.
__global__ void __launch_bounds__(512, 2)
flash_fast(const ubf* __restrict__ Q, const ubf* __restrict__ Kh,
           const ubf* __restrict__ Vt, ubf* __restrict__ AO) {
  __shared__ char lds[65536];
  const int tid = threadIdx.x, lane = tid & 63, w = tid >> 6;
  const int grp = w >> 2, wq = w & 3, tin = tid & 255;
  const int l31 = lane & 31, hi = lane >> 5;
  const int bh = blockIdx.x;
  const int qb = blockIdx.y;
  const int b = bh >> 4, h = bh & 15;
  const int k00 = grp * (S_ / 2);
  constexpr int NT = (S_ / 2) / 64;  // 16 KV tiles per group

  const ubf* Qrow = Q + ((size_t)bh * S_ + qb * 128 + wq * 32 + l31) * D_;
  bh8 q4[4];
#pragma unroll
  for (int kf = 0; kf < 4; kf++) q4[kf] = *(const bh8*)(Qrow + kf * 16 + hi * 8);

  fx16 acc0, acc1, ZF;
#pragma unroll
  for (int i = 0; i < 16; i++) { acc0[i] = 0.f; acc1[i] = 0.f; ZF[i] = 0.f; }
  float2 lr2 = make_float2(0.f, 0.f);

  const ubf* Kg = Kh + (size_t)bh * S_ * D_;
  const ubf* Vg = Vt + (size_t)bh * D_ * S_;
  char* Kbase = lds + grp * 32768;

  auto stage = [&](int buf, int k0) {
    char* Kb = Kbase + buf * 16384;
#pragma unroll
    for (int i = 0; i < 2; i++) {
      int s = i * 256 + tin;
      int row = s >> 3, cc = s & 7;
      int sw = cc ^ (row & 7);  // pre-swizzled global source (rule 21)
      gl_lds16(Kg + (size_t)(k0 + row) * D_ + sw * 8,
               Kb + (i * 256 + (tin & 192)) * 16);
      gl_lds16(Vg + (size_t)row * S_ + k0 + sw * 8,
               Kb + 8192 + (i * 256 + (tin & 192)) * 16);
    }
  };

  stage(0, k00);  // 4 outstanding

  for (int t = 0; t < NT; t++) {
    int cur = t & 1;
    if (t + 1 < NT) {
      stage(cur ^ 1, k00 + (t + 1) * 64);               // 8 outstanding
      asm volatile("s_waitcnt vmcnt(4)" ::: "memory");  // own tile-t loads done
    } else {
      asm volatile("s_waitcnt vmcnt(0)" ::: "memory");
    }
    __builtin_amdgcn_s_barrier();
    const char* Kc = Kbase + cur * 16384;
    const char* Vc = Kc + 8192;

#pragma unroll
    for (int h2 = 0; h2 < 2; h2++) {
      fx16 sc;
      __builtin_amdgcn_s_setprio(1);
      {
        int ch = hi ^ (l31 & 7);
        bh8 ak = *(const bh8*)(Kc + (h2 * 32 + l31) * 128 + ch * 16);
        sc = __builtin_amdgcn_mfma_f32_32x32x16_bf16(ak, q4[0], ZF, 0, 0, 0);
      }
#pragma unroll
      for (int kf = 1; kf < 4; kf++) {
        int ch = (2 * kf + hi) ^ (l31 & 7);
        bh8 ak = *(const bh8*)(Kc + (h2 * 32 + l31) * 128 + ch * 16);
        sc = __builtin_amdgcn_mfma_f32_32x32x16_bf16(ak, q4[kf], sc, 0, 0, 0);
      }
      __builtin_amdgcn_s_setprio(0);

#pragma unroll
      for (int i = 0; i < 8; i++) {
        float p0 = __builtin_amdgcn_exp2f(sc[2 * i]);      // raw v_exp_f32
        float p1 = __builtin_amdgcn_exp2f(sc[2 * i + 1]);  // (no OCML fixups)
        sc[2 * i] = p0; sc[2 * i + 1] = p1;
        lr2.x += p0; lr2.y += p1;
      }

      unsigned pk[8];
#pragma unroll
      for (int i = 0; i < 8; i++) pk[i] = cvtpk(sc[2 * i], sc[2 * i + 1]);
      pl32swap(pk[0], pk[2]); pl32swap(pk[1], pk[3]);
      pl32swap(pk[4], pk[6]); pl32swap(pk[5], pk[7]);

      __builtin_amdgcn_s_setprio(1);
#pragma unroll
      for (int kk = 0; kk < 2; kk++) {
        int KF = 2 * h2 + kk;
        int ch = (2 * KF + hi) ^ (l31 & 7);
        bh8 bv0 = *(const bh8*)(Vc + l31 * 128 + ch * 16);
        bh8 bv1 = *(const bh8*)(Vc + (32 + l31) * 128 + ch * 16);
        unsigned wa[4] = {pk[4 * kk], pk[4 * kk + 1], pk[4 * kk + 2], pk[4 * kk + 3]};
        bh8 pa = *(bh8*)wa;
        acc0 = __builtin_amdgcn_mfma_f32_32x32x16_bf16(pa, bv0, acc0, 0, 0, 0);
        acc1 = __builtin_amdgcn_mfma_f32_32x32x16_bf16(pa, bv1, acc1, 0, 0, 0);
      }
      __builtin_amdgcn_s_setprio(0);
    }
    __builtin_amdgcn_s_barrier();
  }

  // ---- in-block merge of the two KV-groups (LDS scratch reuses tile space)
  float lrun = lr2.x + lr2.y;
  float lsum = lrun + __shfl_xor(lrun, 32);  // per q = l31 (within group)
  float* shacc = (float*)lds;                // [4 waves][64 lanes][34]
  float* shml  = (float*)(lds + 34816);      // [128 q rows]
  if (grp == 1) {
    float* p = shacc + (size_t)(wq * 64 + lane) * 34;
#pragma unroll
    for (int r = 0; r < 16; r++) { p[r] = acc0[r]; p[16 + r] = acc1[r]; }
    if (hi == 0) shml[wq * 32 + l31] = lsum;
  }
  __syncthreads();
  if (grp == 0) {
    const float* p = shacc + (size_t)(wq * 64 + lane) * 34;
#pragma unroll
    for (int r = 0; r < 16; r++) {
      int q2 = ROWQ(r);
      float l0 = __shfl(lsum, q2);
      float inv = 1.0f / (l0 + shml[wq * 32 + q2]);
      size_t base = ((size_t)(b * S_ + qb * 128 + wq * 32 + q2)) * E_ + h * 64;
      AO[base + l31] = f2bf((acc0[r] + p[r]) * inv);
      AO[base + 32 + l31] = f2bf((acc1[r] + p[16 + r]) * inv);
    }
  }
}

// validated r4 PV fragment build via permlane32_swap; PV_STEP(KF) covers keys KF*16..+16
#define PV_STEP(KF, W0, W1, W2, W3)                                             \
    {                                                                           \
      unsigned wa[4] = {W0, W1, W2, W3};                                        \
      bh8 pa = *(bh8*)wa;                                                       \
      int ch = (2 * (KF) + hi) ^ (l31 & 7);                                     \
      bh8 bv0 = *(const bh8*)(Vc + l31 * 128 + ch * 16);                        \
      acc0 = __builtin_amdgcn_mfma_f32_32x32x16_bf16(pa, bv0, acc0, 0, 0, 0);   \
      bh8 bv1 = *(const bh8*)(Vc + (32 + l31) * 128 + ch * 16);                 \
      acc1 = __builtin_amdgcn_mfma_f32_32x32x16_bf16(pa, bv1, acc1, 0, 0, 0);   \
    }

// ---- masked fixup: only runs when mask has nonzeros; overwrites AO with the
// full online-max masked result. Early-exits (cheap) when flagarr is all-zero.
__global__ void __launch_bounds__(256, 4)
flash_masked(const ubf* __restrict__ Q, const ubf* __restrict__ Kh,
             const ubf* __restrict__ Vt, const float* __restrict__ mask,
             const int* __restrict__ flagarr, ubf* __restrict__ AO) {
  __shared__ int anyf;
  if (threadIdx.x == 0) anyf = 0;
  __syncthreads();
  {
    int a = 0;
#pragma unroll
    for (int i = 0; i < 8; i++) a |= flagarr[threadIdx.x + i * 256];
    if (a) anyf = 1;
  }
  __syncthreads();
  if (anyf == 0) return;

  __shared__ ubf Ksm[2][64 * 64];
  __shared__ ubf Vsm[2][64 * 64];
  const int tid = threadIdx.x, lane = tid & 63, w = tid >> 6;
  const int l31 = lane & 31, hi = lane >> 5;
  const int bh = blockIdx.x;
  const int qb = blockIdx.y;
  const int b = bh >> 4, h = bh & 15;
  const int qg = qb * 128 + w * 32 + l31;
  constexpr int NT = S_ / 64;

  const ubf* Qrow = Q + ((size_t)bh * S_ + qg) * D_;
  bh8 q4[4];
#pragma unroll
  for (int kf = 0; kf < 4; kf++) q4[kf] = *(const bh8*)(Qrow + kf * 16 + hi * 8);

  fx16 acc0, acc1;
#pragma unroll
  for (int i = 0; i < 16; i++) { acc0[i] = 0.f; acc1[i] = 0.f; }
  float mrun = -3.0e38f, lrun = 0.f;

  const ubf* Kg = Kh + (size_t)bh * S_ * D_;
  const ubf* Vg = Vt + (size_t)bh * D_ * S_;

  auto stage = [&](int buf, int k0) {
#pragma unroll
    for (int i = 0; i < 2; i++) {
      int s = i * 256 + tid;
      int row = s >> 3, cc = s & 7;
      int sw = cc ^ (row & 7);
      gl_lds16(Kg + (size_t)(k0 + row) * D_ + sw * 8,
               (char*)&Ksm[buf][0] + (i * 256 + (tid & 192)) * 16);
      gl_lds16(Vg + (size_t)row * S_ + k0 + sw * 8,
               (char*)&Vsm[buf][0] + (i * 256 + (tid & 192)) * 16);
    }
  };

  stage(0, 0);
  __syncthreads();

  for (int t = 0; t < NT; t++) {
    int cur = t & 1;
    if (t + 1 < NT) stage(cur ^ 1, (t + 1) * 64);
    const char* Kc = (const char*)&Ksm[cur][0];
    const char* Vc = (const char*)&Vsm[cur][0];

#pragma unroll
    for (int h2 = 0; h2 < 2; h2++) {
      fx16 sc;
#pragma unroll
      for (int i = 0; i < 16; i++) sc[i] = 0.f;
#pragma unroll
      for (int kf = 0; kf < 4; kf++) {
        int ch = (2 * kf + hi) ^ (l31 & 7);
        bh8 ak = *(const bh8*)(Kc + (h2 * 32 + l31) * 128 + ch * 16);
        sc = __builtin_amdgcn_mfma_f32_32x32x16_bf16(ak, q4[kf], sc, 0, 0, 0);
      }
      const float* mq = mask + ((size_t)(b * S_ + qg)) * S_ + t * 64 + h2 * 32;
#pragma unroll
      for (int r = 0; r < 16; r++)
        sc[r] += mq[ROWQ(r)] * (-14426.950408889634f);  // -10000*LOG2E

      float pm = sc[0];
#pragma unroll
      for (int r = 1; r < 16; r++) pm = fmaxf(pm, sc[r]);
      pm = fmaxf(pm, __shfl_xor(pm, 32));
      if (__any(pm - mrun > 11.5415603f)) {  // defer-max (THR=8 nats)
        float mnew = fmaxf(mrun, pm);
        float al = exp2f(mrun - mnew);
        lrun *= al;
#pragma unroll
        for (int r = 0; r < 16; r++) {
          float alr = __shfl(al, ROWQ(r));
          acc0[r] *= alr;
          acc1[r] *= alr;
        }
        mrun = mnew;
      }
      float rsv[4] = {0.f, 0.f, 0.f, 0.f};
#pragma unroll
      for (int i = 0; i < 16; i++) {
        float p = exp2f(sc[i] - mrun);
        sc[i] = p;
        rsv[i & 3] += p;
      }
      lrun += (rsv[0] + rsv[1]) + (rsv[2] + rsv[3]);

      unsigned pk[8];
#pragma unroll
      for (int i = 0; i < 8; i++) pk[i] = cvtpk(sc[2 * i], sc[2 * i + 1]);
      pl32swap(pk[0], pk[2]); pl32swap(pk[1], pk[3]);
      pl32swap(pk[4], pk[6]); pl32swap(pk[5], pk[7]);

      PV_STEP(2 * h2,     pk[0], pk[1], pk[2], pk[3])
      PV_STEP(2 * h2 + 1, pk[4], pk[5], pk[6], pk[7])
    }
    __syncthreads();
  }

  float ltot = lrun + __shfl_xor(lrun, 32);
#pragma unroll
  for (int r = 0; r < 16; r++) {
    int q2 = ROWQ(r);
    float linv = 1.0f / __shfl(ltot, q2);
    size_t base = ((size_t)(b * S_ + qb * 128 + w * 32 + q2)) * E_ + h * 64;
    AO[base + l31] = f2bf(acc0[r] * linv);
    AO[base + 32 + l31] = f2bf(acc1[r] * linv);
  }
}

extern "C" void kernel_launch(void* const* d_in, const int* in_sizes, int n_in,
                              void* d_out, int out_size, void* d_ws, size_t ws_size,
                              hipStream_t stream) {
  (void)in_sizes; (void)n_in; (void)out_size; (void)ws_size;
  const float* q  = (const float*)d_in[0];
  const float* k  = (const float*)d_in[1];
  const float* v  = (const float*)d_in[2];
  const float* mask = (const float*)d_in[3];
  const float* Wq = (const float*)d_in[4];
  const float* bq = (const float*)d_in[5];
  const float* Wk = (const float*)d_in[6];
  const float* bk = (const float*)d_in[7];
  const float* Wv = (const float*)d_in[8];
  const float* bv = (const float*)d_in[9];
  const float* Wo = (const float*)d_in[10];
  const float* bo = (const float*)d_in[11];

  char* ws = (char*)d_ws;
  ubf* X    = (ubf*)(ws);                 // Xq,Xk,Xv bf16, 8 MiB each
  ubf* Wt0  = (ubf*)(ws + 25165824);      // Wq^T,Wk^T,Wv^T,Wo^T 4x2 MiB
  ubf* Qh   = (ubf*)(ws + 33554432);      // [B,H,S,D]
  ubf* Kh   = (ubf*)(ws + 41943040);      // [B,H,S,D]
  ubf* Vt   = (ubf*)(ws + 50331648);      // [B,H,D,S]
  ubf* AO   = (ubf*)(ws + 58720256);      // [4096,1024] bf16
  int* flagarr = (int*)(ws + 67108864);   // 2048 ints

  ubf* Wot = Wt0 + 3145728;

  prep<<<dim3(512, 1, 4), 256, 0, stream>>>(q, k, v, mask, X, flagarr);
  wtrans4<<<dim3(32, 32, 4), 256, 0, stream>>>(Wq, Wk, Wv, Wo, Wt0);

  gemm_qkv<<<dim3(512, 1, 3), 256, 0, stream>>>(X, Wt0, bq, bk, bv, Qh);

  flash_fast<<<dim3(32, 16), 512, 0, stream>>>(Qh, Kh, Vt, AO);
  flash_masked<<<dim3(32, 16), 256, 0, stream>>>(Qh, Kh, Vt, mask, flagarr, AO);

  gemm_out<<<dim3(1024), 256, 0, stream>>>(AO, Wot, bo, (float*)d_out, 1024);
}

// Round 16
// 134.246 us; speedup vs baseline: 1.9392x; 1.9392x over previous
//
#include <hip/hip_runtime.h>
#include <hip/hip_bf16.h>
#include <stdint.h>

#define B_ 2
#define S_ 2048
#define E_ 1024
#define H_ 16
#define D_ 64
#define LOG2E 1.4426950408889634f

typedef unsigned short ubf;
typedef __attribute__((ext_vector_type(8))) short bh8;    // 8 bf16 (4 VGPRs) MFMA A/B frag
typedef __attribute__((ext_vector_type(4))) float fx4;    // 16x16 C/D frag
typedef __attribute__((ext_vector_type(16))) float fx16;  // 32x32 C/D frag

__device__ __forceinline__ ubf f2bf(float f) {
  unsigned u = __float_as_uint(f);
  unsigned r = (u + 0x7fffu + ((u >> 16) & 1u)) >> 16;  // RNE
  return (ubf)r;
}

__device__ __forceinline__ unsigned cvtpk(float lo, float hi2) {
  unsigned r;
  asm("v_cvt_pk_bf16_f32 %0, %1, %2" : "=v"(r) : "v"(lo), "v"(hi2));
  return r;
}

// validated r4: after pl32swap(a,b): a = [a.low32 | b.low32], b = [a.high32 | b.high32]
__device__ __forceinline__ void pl32swap(unsigned& a, unsigned& b) {
  asm("v_permlane32_swap_b32 %0, %1" : "+v"(a), "+v"(b));
}

__device__ __forceinline__ void gl_lds16(const void* g, void* l) {
  __builtin_amdgcn_global_load_lds(
      (const __attribute__((address_space(1))) void*)g,
      (__attribute__((address_space(3))) void*)l, 16, 0, 0);
}

// ---------------- prepass: z<3: fp32->bf16 convert of q/k/v; z=3: mask scan
__global__ void prep(const float* __restrict__ q, const float* __restrict__ k,
                     const float* __restrict__ v, const float* __restrict__ mask,
                     ubf* __restrict__ dst0, int* __restrict__ flagarr) {
  const int z = blockIdx.z;
  const int tid = threadIdx.x;
  const int stride = gridDim.x * blockDim.x;
  if (z == 3) {
    int any = 0;
    const int n4m = (B_ * S_ * S_) / 4;
    for (int j = blockIdx.x * blockDim.x + tid; j < n4m; j += stride) {
      float4 x = ((const float4*)mask)[j];
      any |= (x.x != 0.f) | (x.y != 0.f) | (x.z != 0.f) | (x.w != 0.f);
    }
    int wany = __any(any != 0) ? 1 : 0;
    if ((tid & 63) == 0) flagarr[blockIdx.x * 4 + (tid >> 6)] = wany;
    return;
  }
  const float* src = (z == 0) ? q : (z == 1) ? k : v;
  ubf* dst = dst0 + (size_t)z * (B_ * S_ * E_);
  const int n4 = (B_ * S_ * E_) / 4;
  for (int j = blockIdx.x * blockDim.x + tid; j < n4; j += stride) {
    float4 x = ((const float4*)src)[j];
    ushort4 o;
    o.x = f2bf(x.x); o.y = f2bf(x.y); o.z = f2bf(x.z); o.w = f2bf(x.w);
    ((ushort4*)dst)[j] = o;
  }
}

// ---------------- prepass: weight transpose+convert  Wt[n][k] = W[k][n] (bf16)
__global__ void wtrans4(const float* __restrict__ Wq, const float* __restrict__ Wk,
                        const float* __restrict__ Wv, const float* __restrict__ Wo,
                        ubf* __restrict__ Wt0) {
  __shared__ float t[32][33];
  int z = blockIdx.z;
  const float* W = (z == 0) ? Wq : (z == 1) ? Wk : (z == 2) ? Wv : Wo;
  ubf* Wt = Wt0 + (size_t)z * (E_ * E_);
  int kb = blockIdx.x, nb = blockIdx.y;
  int c = threadIdx.x & 31, r0 = threadIdx.x >> 5;
#pragma unroll
  for (int rr = 0; rr < 32; rr += 8)
    t[r0 + rr][c] = W[(size_t)(kb * 32 + r0 + rr) * E_ + nb * 32 + c];
  __syncthreads();
#pragma unroll
  for (int rr = 0; rr < 32; rr += 8)
    Wt[(size_t)(nb * 32 + r0 + rr) * E_ + kb * 32 + c] = f2bf(t[c][r0 + rr]);
}

// ================= fused QKV projection GEMM (128x64 tile, 6 blocks/CU) =====
// Swizzle (validated r7): slot = cc ^ ((row>>1)&3) — conflict-free for 64B rows.
// T1 XCD swizzle (validated r10: FETCH 82->37 MB).
__global__ void __launch_bounds__(256, 6)
gemm_qkv(const ubf* __restrict__ X, const ubf* __restrict__ Wt,
         const float* __restrict__ bq, const float* __restrict__ bk,
         const float* __restrict__ bv, ubf* __restrict__ Out) {
  constexpr int K = 1024;
  __shared__ ubf Asm[2][128 * 32];
  __shared__ ubf Bsm[2][64 * 32];
  const int z = blockIdx.z;
  const ubf* A  = (z == 2) ? (Wt + 2u * 1048576u) : (X + (size_t)z * 4194304u);
  const ubf* Bt = (z == 2) ? (X + 2u * 4194304u) : (Wt + (size_t)z * 1048576u);
  const float* bias = (z == 0) ? bq : (z == 1) ? bk : bv;
  ubf* Cout = Out + (size_t)z * 4194304u;

  const int bx0 = blockIdx.x;
  const int swz = (bx0 & 7) * 64 + (bx0 >> 3);  // XCD-contiguous chunks (T1)
  int bm, bn;
  if (z == 2) {
    bm = (swz >> 3) & 7;
    bn = ((swz >> 6) << 3) | (swz & 7);
  } else {
    bm = swz >> 4;
    bn = swz & 15;
  }

  const int tid = threadIdx.x;
  const int lane = tid & 63, w = tid >> 6;
  const int wm = w >> 1, wn = w & 1;
  const int g = lane >> 4, c15 = lane & 15;

  const fx4 FZ = {0.f, 0.f, 0.f, 0.f};
  fx4 acc[4][2];
#pragma unroll
  for (int m = 0; m < 4; m++)
#pragma unroll
    for (int n = 0; n < 2; n++) acc[m][n] = FZ;

  auto stage = [&](int buf, int k0) {
#pragma unroll
    for (int i = 0; i < 2; i++) {  // A: 128 rows
      int s = i * 256 + tid;
      int row = s >> 2, cc = s & 3;
      int sc = cc ^ ((row >> 1) & 3);
      gl_lds16(A + (size_t)(bm * 128 + row) * K + k0 + sc * 8,
               (char*)&Asm[buf][0] + (i * 256 + (tid & 192)) * 16);
    }
    {  // B: 64 rows
      int row = tid >> 2, cc = tid & 3;
      int sc = cc ^ ((row >> 1) & 3);
      gl_lds16(Bt + (size_t)(bn * 64 + row) * K + k0 + sc * 8,
               (char*)&Bsm[buf][0] + (tid & 192) * 16);
    }
  };

  stage(0, 0);
  for (int t = 0; t < K / 32; t++) {
    int cur = t & 1;
    if (t + 1 < K / 32) {
      stage(cur ^ 1, (t + 1) * 32);
      asm volatile("s_waitcnt vmcnt(3)" ::: "memory");
    } else {
      asm volatile("s_waitcnt vmcnt(0)" ::: "memory");
    }
    __builtin_amdgcn_s_barrier();
    bh8 a[4], b[2];
#pragma unroll
    for (int m = 0; m < 4; m++) {
      int row = wm * 64 + m * 16 + c15;
      int ch = g ^ ((row >> 1) & 3);
      a[m] = *(const bh8*)((const char*)&Asm[cur][0] + row * 64 + ch * 16);
    }
#pragma unroll
    for (int n = 0; n < 2; n++) {
      int row = wn * 32 + n * 16 + c15;
      int ch = g ^ ((row >> 1) & 3);
      b[n] = *(const bh8*)((const char*)&Bsm[cur][0] + row * 64 + ch * 16);
    }
    __builtin_amdgcn_s_setprio(1);
#pragma unroll
    for (int m = 0; m < 4; m++)
#pragma unroll
      for (int n = 0; n < 2; n++)
        acc[m][n] = __builtin_amdgcn_mfma_f32_16x16x32_bf16(a[m], b[n], acc[m][n], 0, 0, 0);
    __builtin_amdgcn_s_setprio(0);
    __builtin_amdgcn_s_barrier();
  }

#pragma unroll
  for (int m = 0; m < 4; m++) {
    int rbase = bm * 128 + wm * 64 + m * 16 + g * 4;
#pragma unroll
    for (int n = 0; n < 2; n++) {
      int col = bn * 64 + wn * 32 + n * 16 + c15;
#pragma unroll
      for (int r = 0; r < 4; r++) {
        int mrow = rbase + r;
        float val = acc[m][n][r];
        if (z <= 1) {
          val = val + bias[col];
          if (z == 0) val *= 0.125f * LOG2E;  // fold 1/sqrt(D) and log2 domain
          int bb = mrow >> 11, ss = mrow & 2047, hh = col >> 6, dd = col & 63;
          Cout[((size_t)(bb * H_ + hh) * S_ + ss) * D_ + dd] = f2bf(val);
        } else {
          val = val + bias[mrow];
          int bb = col >> 11, ss = col & 2047, hh = mrow >> 6, dd = mrow & 63;
          Cout[((size_t)(bb * H_ + hh) * D_ + dd) * S_ + ss] = f2bf(val);
        }
      }
    }
  }
}

// ================= output GEMM (64x64 tile, 4 blocks/CU): d_out = AO@Wo^T + bo =====
__global__ void __launch_bounds__(256, 4)
gemm_out(const ubf* __restrict__ A, const ubf* __restrict__ Bt,
         const float* __restrict__ bias, float* __restrict__ Cout, int N) {
  constexpr int K = 1024;
  __shared__ ubf Asm[2][64 * 32];
  __shared__ ubf Bsm[2][64 * 32];
  const int tid = threadIdx.x;
  const int lane = tid & 63, w = tid >> 6;
  const int wm = w >> 1, wn = w & 1;
  const int bid = blockIdx.x;
  const int swz = (bid & 7) * 128 + (bid >> 3);  // T1
  const int bm = swz >> 4, bn = swz & 15;
  const int g = lane >> 4, c15 = lane & 15;

  const fx4 FZ = {0.f, 0.f, 0.f, 0.f};
  fx4 acc[2][2];
#pragma unroll
  for (int m = 0; m < 2; m++)
#pragma unroll
    for (int n = 0; n < 2; n++) acc[m][n] = FZ;

  auto stage = [&](int buf, int k0) {
    int row = tid >> 2, cc = tid & 3;
    int sc = cc ^ ((row >> 1) & 3);
    gl_lds16(A + (size_t)(bm * 64 + row) * K + k0 + sc * 8,
             (char*)&Asm[buf][0] + (tid & 192) * 16);
    gl_lds16(Bt + (size_t)(bn * 64 + row) * K + k0 + sc * 8,
             (char*)&Bsm[buf][0] + (tid & 192) * 16);
  };

  stage(0, 0);
  for (int t = 0; t < K / 32; t++) {
    int cur = t & 1;
    if (t + 1 < K / 32) {
      stage(cur ^ 1, (t + 1) * 32);
      asm volatile("s_waitcnt vmcnt(2)" ::: "memory");
    } else {
      asm volatile("s_waitcnt vmcnt(0)" ::: "memory");
    }
    __builtin_amdgcn_s_barrier();
    bh8 a[2], b[2];
#pragma unroll
    for (int m = 0; m < 2; m++) {
      int row = wm * 32 + m * 16 + c15;
      int ch = g ^ ((row >> 1) & 3);
      a[m] = *(const bh8*)((const char*)&Asm[cur][0] + row * 64 + ch * 16);
    }
#pragma unroll
    for (int n = 0; n < 2; n++) {
      int row = wn * 32 + n * 16 + c15;
      int ch = g ^ ((row >> 1) & 3);
      b[n] = *(const bh8*)((const char*)&Bsm[cur][0] + row * 64 + ch * 16);
    }
    __builtin_amdgcn_s_setprio(1);
#pragma unroll
    for (int m = 0; m < 2; m++)
#pragma unroll
      for (int n = 0; n < 2; n++)
        acc[m][n] = __builtin_amdgcn_mfma_f32_16x16x32_bf16(a[m], b[n], acc[m][n], 0, 0, 0);
    __builtin_amdgcn_s_setprio(0);
    __builtin_amdgcn_s_barrier();
  }

#pragma unroll
  for (int m = 0; m < 2; m++) {
    int rbase = bm * 64 + wm * 32 + m * 16 + g * 4;
#pragma unroll
    for (int n = 0; n < 2; n++) {
      int col = bn * 64 + wn * 32 + n * 16 + c15;
#pragma unroll
      for (int r = 0; r < 4; r++)
        Cout[(size_t)(rbase + r) * N + col] = acc[m][n][r] + bias[col];
    }
  }
}

// ================= flash attention =================
// Q[B,H,S,D] (pre-scaled by 0.125*LOG2E), K[B,H,S,D], V^T[B,H,D,S]
// Swapped QK^T: lane owns q = lane&31; key row = ROWQ(r).
// C/D map (32x32): col=lane&31, row=(r&3)+8*(r>>2)+4*(lane>>5)   [m74/m101]
#define ROWQ(r) (((r) & 3) + 8 * ((r) >> 2) + 4 * hi)

// ---- fast path: 512 threads = 2 KV-groups x 4 waves; in-block LDS merge.
// Writes AO bf16 directly — no fp32 partials, no combine kernel.
__global__ void __launch_bounds__(512, 2)
flash_fast(const ubf* __restrict__ Q, const ubf* __restrict__ Kh,
           const ubf* __restrict__ Vt, ubf* __restrict__ AO) {
  __shared__ char lds[65536];
  const int tid = threadIdx.x, lane = tid & 63, w = tid >> 6;
  const int grp = w >> 2, wq = w & 3, tin = tid & 255;
  const int l31 = lane & 31, hi = lane >> 5;
  const int bh = blockIdx.x;
  const int qb = blockIdx.y;
  const int b = bh >> 4, h = bh & 15;
  const int k00 = grp * (S_ / 2);
  constexpr int NT = (S_ / 2) / 64;  // 16 KV tiles per group

  const ubf* Qrow = Q + ((size_t)bh * S_ + qb * 128 + wq * 32 + l31) * D_;
  bh8 q4[4];
#pragma unroll
  for (int kf = 0; kf < 4; kf++) q4[kf] = *(const bh8*)(Qrow + kf * 16 + hi * 8);

  fx16 acc0, acc1, ZF;
#pragma unroll
  for (int i = 0; i < 16; i++) { acc0[i] = 0.f; acc1[i] = 0.f; ZF[i] = 0.f; }
  float2 lr2 = make_float2(0.f, 0.f);

  const ubf* Kg = Kh + (size_t)bh * S_ * D_;
  const ubf* Vg = Vt + (size_t)bh * D_ * S_;
  char* Kbase = lds + grp * 32768;

  auto stage = [&](int buf, int k0) {
    char* Kb = Kbase + buf * 16384;
#pragma unroll
    for (int i = 0; i < 2; i++) {
      int s = i * 256 + tin;
      int row = s >> 3, cc = s & 7;
      int sw = cc ^ (row & 7);  // pre-swizzled global source (rule 21)
      gl_lds16(Kg + (size_t)(k0 + row) * D_ + sw * 8,
               Kb + (i * 256 + (tin & 192)) * 16);
      gl_lds16(Vg + (size_t)row * S_ + k0 + sw * 8,
               Kb + 8192 + (i * 256 + (tin & 192)) * 16);
    }
  };

  stage(0, k00);  // 4 outstanding

  for (int t = 0; t < NT; t++) {
    int cur = t & 1;
    if (t + 1 < NT) {
      stage(cur ^ 1, k00 + (t + 1) * 64);               // 8 outstanding
      asm volatile("s_waitcnt vmcnt(4)" ::: "memory");  // own tile-t loads done
    } else {
      asm volatile("s_waitcnt vmcnt(0)" ::: "memory");
    }
    __builtin_amdgcn_s_barrier();
    const char* Kc = Kbase + cur * 16384;
    const char* Vc = Kc + 8192;

#pragma unroll
    for (int h2 = 0; h2 < 2; h2++) {
      fx16 sc;
      __builtin_amdgcn_s_setprio(1);
      {
        int ch = hi ^ (l31 & 7);
        bh8 ak = *(const bh8*)(Kc + (h2 * 32 + l31) * 128 + ch * 16);
        sc = __builtin_amdgcn_mfma_f32_32x32x16_bf16(ak, q4[0], ZF, 0, 0, 0);
      }
#pragma unroll
      for (int kf = 1; kf < 4; kf++) {
        int ch = (2 * kf + hi) ^ (l31 & 7);
        bh8 ak = *(const bh8*)(Kc + (h2 * 32 + l31) * 128 + ch * 16);
        sc = __builtin_amdgcn_mfma_f32_32x32x16_bf16(ak, q4[kf], sc, 0, 0, 0);
      }
      __builtin_amdgcn_s_setprio(0);

#pragma unroll
      for (int i = 0; i < 8; i++) {
        float p0 = __builtin_amdgcn_exp2f(sc[2 * i]);      // raw v_exp_f32
        float p1 = __builtin_amdgcn_exp2f(sc[2 * i + 1]);  // (no OCML fixups)
        sc[2 * i] = p0; sc[2 * i + 1] = p1;
        lr2.x += p0; lr2.y += p1;
      }

      unsigned pk[8];
#pragma unroll
      for (int i = 0; i < 8; i++) pk[i] = cvtpk(sc[2 * i], sc[2 * i + 1]);
      pl32swap(pk[0], pk[2]); pl32swap(pk[1], pk[3]);
      pl32swap(pk[4], pk[6]); pl32swap(pk[5], pk[7]);

      __builtin_amdgcn_s_setprio(1);
#pragma unroll
      for (int kk = 0; kk < 2; kk++) {
        int KF = 2 * h2 + kk;
        int ch = (2 * KF + hi) ^ (l31 & 7);
        bh8 bv0 = *(const bh8*)(Vc + l31 * 128 + ch * 16);
        bh8 bv1 = *(const bh8*)(Vc + (32 + l31) * 128 + ch * 16);
        unsigned wa[4] = {pk[4 * kk], pk[4 * kk + 1], pk[4 * kk + 2], pk[4 * kk + 3]};
        bh8 pa = *(bh8*)wa;
        acc0 = __builtin_amdgcn_mfma_f32_32x32x16_bf16(pa, bv0, acc0, 0, 0, 0);
        acc1 = __builtin_amdgcn_mfma_f32_32x32x16_bf16(pa, bv1, acc1, 0, 0, 0);
      }
      __builtin_amdgcn_s_setprio(0);
    }
    __builtin_amdgcn_s_barrier();
  }

  // ---- in-block merge of the two KV-groups (LDS scratch reuses tile space)
  float lrun = lr2.x + lr2.y;
  float lsum = lrun + __shfl_xor(lrun, 32);  // per q = l31 (within group)
  float* shacc = (float*)lds;                // [4 waves][64 lanes][34]
  float* shml  = (float*)(lds + 34816);      // [128 q rows]
  if (grp == 1) {
    float* p = shacc + (size_t)(wq * 64 + lane) * 34;
#pragma unroll
    for (int r = 0; r < 16; r++) { p[r] = acc0[r]; p[16 + r] = acc1[r]; }
    if (hi == 0) shml[wq * 32 + l31] = lsum;
  }
  __syncthreads();
  if (grp == 0) {
    const float* p = shacc + (size_t)(wq * 64 + lane) * 34;
#pragma unroll
    for (int r = 0; r < 16; r++) {
      int q2 = ROWQ(r);
      float l0 = __shfl(lsum, q2);
      float inv = 1.0f / (l0 + shml[wq * 32 + q2]);
      size_t base = ((size_t)(b * S_ + qb * 128 + wq * 32 + q2)) * E_ + h * 64;
      AO[base + l31] = f2bf((acc0[r] + p[r]) * inv);
      AO[base + 32 + l31] = f2bf((acc1[r] + p[16 + r]) * inv);
    }
  }
}

// validated r4 PV fragment build via permlane32_swap; PV_STEP(KF) covers keys KF*16..+16
#define PV_STEP(KF, W0, W1, W2, W3)                                             \
    {                                                                           \
      unsigned wa[4] = {W0, W1, W2, W3};                                        \
      bh8 pa = *(bh8*)wa;                                                       \
      int ch = (2 * (KF) + hi) ^ (l31 & 7);                                     \
      bh8 bv0 = *(const bh8*)(Vc + l31 * 128 + ch * 16);                        \
      acc0 = __builtin_amdgcn_mfma_f32_32x32x16_bf16(pa, bv0, acc0, 0, 0, 0);   \
      bh8 bv1 = *(const bh8*)(Vc + (32 + l31) * 128 + ch * 16);                 \
      acc1 = __builtin_amdgcn_mfma_f32_32x32x16_bf16(pa, bv1, acc1, 0, 0, 0);   \
    }

// ---- masked fixup: only runs when mask has nonzeros; overwrites AO with the
// full online-max masked result. Early-exits (cheap) when flagarr is all-zero.
__global__ void __launch_bounds__(256, 4)
flash_masked(const ubf* __restrict__ Q, const ubf* __restrict__ Kh,
             const ubf* __restrict__ Vt, const float* __restrict__ mask,
             const int* __restrict__ flagarr, ubf* __restrict__ AO) {
  __shared__ int anyf;
  if (threadIdx.x == 0) anyf = 0;
  __syncthreads();
  {
    int a = 0;
#pragma unroll
    for (int i = 0; i < 8; i++) a |= flagarr[threadIdx.x + i * 256];
    if (a) anyf = 1;
  }
  __syncthreads();
  if (anyf == 0) return;

  __shared__ ubf Ksm[2][64 * 64];
  __shared__ ubf Vsm[2][64 * 64];
  const int tid = threadIdx.x, lane = tid & 63, w = tid >> 6;
  const int l31 = lane & 31, hi = lane >> 5;
  const int bh = blockIdx.x;
  const int qb = blockIdx.y;
  const int b = bh >> 4, h = bh & 15;
  const int qg = qb * 128 + w * 32 + l31;
  constexpr int NT = S_ / 64;

  const ubf* Qrow = Q + ((size_t)bh * S_ + qg) * D_;
  bh8 q4[4];
#pragma unroll
  for (int kf = 0; kf < 4; kf++) q4[kf] = *(const bh8*)(Qrow + kf * 16 + hi * 8);

  fx16 acc0, acc1;
#pragma unroll
  for (int i = 0; i < 16; i++) { acc0[i] = 0.f; acc1[i] = 0.f; }
  float mrun = -3.0e38f, lrun = 0.f;

  const ubf* Kg = Kh + (size_t)bh * S_ * D_;
  const ubf* Vg = Vt + (size_t)bh * D_ * S_;

  auto stage = [&](int buf, int k0) {
#pragma unroll
    for (int i = 0; i < 2; i++) {
      int s = i * 256 + tid;
      int row = s >> 3, cc = s & 7;
      int sw = cc ^ (row & 7);
      gl_lds16(Kg + (size_t)(k0 + row) * D_ + sw * 8,
               (char*)&Ksm[buf][0] + (i * 256 + (tid & 192)) * 16);
      gl_lds16(Vg + (size_t)row * S_ + k0 + sw * 8,
               (char*)&Vsm[buf][0] + (i * 256 + (tid & 192)) * 16);
    }
  };

  stage(0, 0);
  __syncthreads();

  for (int t = 0; t < NT; t++) {
    int cur = t & 1;
    if (t + 1 < NT) stage(cur ^ 1, (t + 1) * 64);
    const char* Kc = (const char*)&Ksm[cur][0];
    const char* Vc = (const char*)&Vsm[cur][0];

#pragma unroll
    for (int h2 = 0; h2 < 2; h2++) {
      fx16 sc;
#pragma unroll
      for (int i = 0; i < 16; i++) sc[i] = 0.f;
#pragma unroll
      for (int kf = 0; kf < 4; kf++) {
        int ch = (2 * kf + hi) ^ (l31 & 7);
        bh8 ak = *(const bh8*)(Kc + (h2 * 32 + l31) * 128 + ch * 16);
        sc = __builtin_amdgcn_mfma_f32_32x32x16_bf16(ak, q4[kf], sc, 0, 0, 0);
      }
      const float* mq = mask + ((size_t)(b * S_ + qg)) * S_ + t * 64 + h2 * 32;
#pragma unroll
      for (int r = 0; r < 16; r++)
        sc[r] += mq[ROWQ(r)] * (-14426.950408889634f);  // -10000*LOG2E

      float pm = sc[0];
#pragma unroll
      for (int r = 1; r < 16; r++) pm = fmaxf(pm, sc[r]);
      pm = fmaxf(pm, __shfl_xor(pm, 32));
      if (__any(pm - mrun > 11.5415603f)) {  // defer-max (THR=8 nats)
        float mnew = fmaxf(mrun, pm);
        float al = exp2f(mrun - mnew);
        lrun *= al;
#pragma unroll
        for (int r = 0; r < 16; r++) {
          float alr = __shfl(al, ROWQ(r));
          acc0[r] *= alr;
          acc1[r] *= alr;
        }
        mrun = mnew;
      }
      float rsv[4] = {0.f, 0.f, 0.f, 0.f};
#pragma unroll
      for (int i = 0; i < 16; i++) {
        float p = exp2f(sc[i] - mrun);
        sc[i] = p;
        rsv[i & 3] += p;
      }
      lrun += (rsv[0] + rsv[1]) + (rsv[2] + rsv[3]);

      unsigned pk[8];
#pragma unroll
      for (int i = 0; i < 8; i++) pk[i] = cvtpk(sc[2 * i], sc[2 * i + 1]);
      pl32swap(pk[0], pk[2]); pl32swap(pk[1], pk[3]);
      pl32swap(pk[4], pk[6]); pl32swap(pk[5], pk[7]);

      PV_STEP(2 * h2,     pk[0], pk[1], pk[2], pk[3])
      PV_STEP(2 * h2 + 1, pk[4], pk[5], pk[6], pk[7])
    }
    __syncthreads();
  }

  float ltot = lrun + __shfl_xor(lrun, 32);
#pragma unroll
  for (int r = 0; r < 16; r++) {
    int q2 = ROWQ(r);
    float linv = 1.0f / __shfl(ltot, q2);
    size_t base = ((size_t)(b * S_ + qb * 128 + w * 32 + q2)) * E_ + h * 64;
    AO[base + l31] = f2bf(acc0[r] * linv);
    AO[base + 32 + l31] = f2bf(acc1[r] * linv);
  }
}

extern "C" void kernel_launch(void* const* d_in, const int* in_sizes, int n_in,
                              void* d_out, int out_size, void* d_ws, size_t ws_size,
                              hipStream_t stream) {
  (void)in_sizes; (void)n_in; (void)out_size; (void)ws_size;
  const float* q  = (const float*)d_in[0];
  const float* k  = (const float*)d_in[1];
  const float* v  = (const float*)d_in[2];
  const float* mask = (const float*)d_in[3];
  const float* Wq = (const float*)d_in[4];
  const float* bq = (const float*)d_in[5];
  const float* Wk = (const float*)d_in[6];
  const float* bk = (const float*)d_in[7];
  const float* Wv = (const float*)d_in[8];
  const float* bv = (const float*)d_in[9];
  const float* Wo = (const float*)d_in[10];
  const float* bo = (const float*)d_in[11];

  char* ws = (char*)d_ws;
  ubf* X    = (ubf*)(ws);                 // Xq,Xk,Xv bf16, 8 MiB each
  ubf* Wt0  = (ubf*)(ws + 25165824);      // Wq^T,Wk^T,Wv^T,Wo^T 4x2 MiB
  ubf* Qh   = (ubf*)(ws + 33554432);      // [B,H,S,D]
  ubf* Kh   = (ubf*)(ws + 41943040);      // [B,H,S,D]
  ubf* Vt   = (ubf*)(ws + 50331648);      // [B,H,D,S]
  ubf* AO   = (ubf*)(ws + 58720256);      // [4096,1024] bf16
  int* flagarr = (int*)(ws + 67108864);   // 2048 ints

  ubf* Wot = Wt0 + 3145728;

  prep<<<dim3(512, 1, 4), 256, 0, stream>>>(q, k, v, mask, X, flagarr);
  wtrans4<<<dim3(32, 32, 4), 256, 0, stream>>>(Wq, Wk, Wv, Wo, Wt0);

  gemm_qkv<<<dim3(512, 1, 3), 256, 0, stream>>>(X, Wt0, bq, bk, bv, Qh);

  flash_fast<<<dim3(32, 16), 512, 0, stream>>>(Qh, Kh, Vt, AO);
  flash_masked<<<dim3(32, 16), 256, 0, stream>>>(Qh, Kh, Vt, mask, flagarr, AO);

  gemm_out<<<dim3(1024), 256, 0, stream>>>(AO, Wot, bo, (float*)d_out, 1024);
}